// Round 8
// baseline (10581.221 us; speedup 1.0000x reference)
//
#include <hip/hip_runtime.h>
#include <cmath>

// ESN forward scan on MI355X — round 11 (= round 10 with the DPP builtin's
// ctrl made a compile-time template constant; that was the only compile
// error).
//
// Round-9 post-mortem: 8.70 ms (-1.9%, micro-levers exhausted), BUT the
// counters exposed the real remaining term: WRITE_SIZE scales exactly with
// publish bytes (1.14->2.19 GB at 8->16 replicas) and FETCH ~doubled too.
// => sc0 sc1 publish stores STREAM THROUGH to HBM (no MALL allocation,
// stale-line invalidate), and every poll READ-MISSES to HBM. The exchange
// hop is HBM-latency-bound (~0.7 us round trip) — the dominant step term.
//
// Round-10/11 levers (independent, separable in counters):
//   1. Publish via returnless global_atomic_swap_x2 (device-scope by
//      default, m20). Atomics execute AT the coherence point and allocate
//      in the Infinity Cache: the 512 KB ping-pong becomes MALL-resident.
//      Signature if right: FETCH collapses (597 -> <150 MB), WRITE drops,
//      visibility hop loses ~200-400 ns. (Poll loads keep sc0 sc1 — the
//      memory-side MALL is transparent to them; they hit it when present.)
//   2. Reduce: 6-level __shfl_xor butterfly (6 DEPENDENT ds_bpermute,
//      ~720 cyc ≈ 0.3 us pre-publish critical path) -> 4 DPP row_ror adds
//      (within-16 rotate reduce, VALU speed) + 3 PARALLEL cross-group
//      fetches (ds_swizzle xor16 + ds_bpermute xor32/xor48, latencies
//      overlap). Chain ~180 cyc.
//
// Predicted: dur 6.3-7.3 ms, FETCH <150 MB, WRITE <300 MB (or unchanged if
// MALL write-through — FETCH still collapses), VALUBusy 24-28%. If FETCH
// does NOT collapse: atomics don't allocate in MALL either; exchange is
// irreducibly HBM-latency-bound and the structure is converged.

#define T_STEPS  4096
#define R_SIZE   4096
#define I_SIZE   3
#define OUT_COLS (R_SIZE + I_SIZE)   // 4099
#define NB       256                 // blocks == CUs; all co-resident
#define BT       256                 // threads per block (4 waves)
#define RPB      16                  // rows per block
#define RPW      4                   // rows per wave
#define NREP     16                  // exchange replicas (fan-in spreading)
#define LEAK     0.1f

typedef _Float16 h2 __attribute__((ext_vector_type(2)));
typedef _Float16 h8 __attribute__((ext_vector_type(8)));
typedef unsigned u32x2 __attribute__((ext_vector_type(2)));
typedef unsigned u32x4 __attribute__((ext_vector_type(4)));

__device__ __forceinline__ float fdot2f(h2 a, h2 b, float c) {
#if __has_builtin(__builtin_amdgcn_fdot2)
    return __builtin_amdgcn_fdot2(a, b, c, false);
#else
    return c + (float)a[0] * (float)b[0] + (float)a[1] * (float)b[1];
#endif
}

// tanh via 2^x: tanh(|s|) = (1-e)/(1+e), e = exp2(-2*log2e*|s|). Error
// ~1e-6, far below the 3.9e-3 fp16 exchange quantization already accepted.
__device__ __forceinline__ float fast_tanhf(float s) {
    float av = __builtin_fabsf(s);
    float e  = __builtin_amdgcn_exp2f(-2.8853900817779268f * av);
    float r  = (1.0f - e) * __builtin_amdgcn_rcpf(1.0f + e);
    return __builtin_copysignf(r, s);
}

// 16 tagged words in flight with L1/L2 bypass, one waitcnt.
__device__ __forceinline__ void poll16(const unsigned* p0, const unsigned* p1,
                                       const unsigned* p2, const unsigned* p3,
                                       u32x4& a0, u32x4& a1, u32x4& a2, u32x4& a3) {
    asm volatile(
        "global_load_dwordx4 %0, %4, off sc0 sc1\n\t"
        "global_load_dwordx4 %1, %5, off sc0 sc1\n\t"
        "global_load_dwordx4 %2, %6, off sc0 sc1\n\t"
        "global_load_dwordx4 %3, %7, off sc0 sc1\n\t"
        "s_waitcnt vmcnt(0)"
        : "=&v"(a0), "=&v"(a1), "=&v"(a2), "=&v"(a3)
        : "v"(p0), "v"(p1), "v"(p2), "v"(p3)
        : "memory");
}

// v_perm-paired tag check: pack two hi-half tags per dword, xor vs splat.
__device__ __forceinline__ unsigned tagbad4(const u32x4& a, unsigned tg2) {
    unsigned t01 = __builtin_amdgcn_perm(a[1], a[0], 0x07060302u) ^ tg2;
    unsigned t23 = __builtin_amdgcn_perm(a[3], a[2], 0x07060302u) ^ tg2;
    return t01 | t23;
}
__device__ __forceinline__ int check16(const u32x4& a0, const u32x4& a1,
                                       const u32x4& a2, const u32x4& a3,
                                       unsigned tg2) {
    unsigned bad = tagbad4(a0, tg2) | tagbad4(a1, tg2) |
                   tagbad4(a2, tg2) | tagbad4(a3, tg2);
    return bad == 0u;
}

// ---- wave-sum, short-chain version ----
// Stage 1: rotate-reduce within each 16-lane DPP row (4 VALU-speed adds):
//   every lane ends with its group's partial sum.
// Stage 2: fetch the other 3 group-partials IN PARALLEL (independent ops:
//   ds_swizzle lane^16 + ds_bpermute lane^32 and lane^48) and add.
template<int CTRL>
__device__ __forceinline__ float dpp_ror_add(float a) {
    int r = __builtin_amdgcn_update_dpp(0, __builtin_bit_cast(int, a),
                                        CTRL, 0xF, 0xF, false);
    return a + __builtin_bit_cast(float, r);
}
__device__ __forceinline__ float wave_sum(float a, int idx32, int idx48) {
    a = dpp_ror_add<0x128>(a);   // row_ror:8
    a = dpp_ror_add<0x124>(a);   // row_ror:4
    a = dpp_ror_add<0x122>(a);   // row_ror:2
    a = dpp_ror_add<0x121>(a);   // row_ror:1
    int ai = __builtin_bit_cast(int, a);
    float b = __builtin_bit_cast(float, __builtin_amdgcn_ds_swizzle(ai, 0x401F)); // lane^16
    float c = __builtin_bit_cast(float, __builtin_amdgcn_ds_bpermute(idx32, ai)); // lane^32
    float d = __builtin_bit_cast(float, __builtin_amdgcn_ds_bpermute(idx48, ai)); // lane^48
    return (a + b) + (c + d);
}

__global__ void __launch_bounds__(BT, 1) esn_kernel(
    const float* __restrict__ Wh,    // [R, R] row-major fp32
    const float* __restrict__ Win,   // [R, 3]
    const float* __restrict__ x,     // [T, 3]
    float* __restrict__ out,         // [T, 4099]
    unsigned* __restrict__ ex0,      // even-step reads: nrep x R dwords
    unsigned* __restrict__ ex1,      // odd-step reads:  nrep x R dwords
    unsigned rep_mask)               // nrep-1 (16/8/1 by ws_size)
{
    __shared__ alignas(16) unsigned short hl[R_SIZE];   // 8 KB fp16 bits
    __shared__ float xs[T_STEPS * I_SIZE];              // 48 KB

    const int tid  = threadIdx.x;
    const int bid  = blockIdx.x;
    const int wv   = tid >> 6;
    const int lane = tid & 63;
    const int r0   = bid * RPB;
    const int idx32 = ((lane ^ 32) << 2);   // bpermute byte indices
    const int idx48 = ((lane ^ 48) << 2);

    // ---- one-time: this wave's 4 Wh rows -> fp16 registers (128 VGPRs) ----
    h8 wreg[RPW * 8];
    #pragma unroll
    for (int rr = 0; rr < RPW; ++rr) {
        const float* src = Wh + (size_t)(r0 + wv * RPW + rr) * R_SIZE;
        #pragma unroll
        for (int j = 0; j < 8; ++j) {
            int e = (j * 64 + lane) * 8;
            float4 a = *(const float4*)(src + e);
            float4 b = *(const float4*)(src + e + 4);
            h8 hv;
            hv[0] = (_Float16)a.x; hv[1] = (_Float16)a.y;
            hv[2] = (_Float16)a.z; hv[3] = (_Float16)a.w;
            hv[4] = (_Float16)b.x; hv[5] = (_Float16)b.y;
            hv[6] = (_Float16)b.z; hv[7] = (_Float16)b.w;
            wreg[rr * 8 + j] = hv;
        }
    }

    // ---- one-time: stage x into LDS ----
    for (int i = tid; i < T_STEPS * I_SIZE; i += BT) xs[i] = x[i];

    // publisher lanes (lane<4) cache their row's Win and fp32 leak state
    float win0 = 0.f, win1 = 0.f, win2 = 0.f;
    if (lane < RPW) {
        int r = r0 + wv * RPW + lane;
        win0 = Win[(size_t)r * I_SIZE + 0];
        win1 = Win[(size_t)r * I_SIZE + 1];
        win2 = Win[(size_t)r * I_SIZE + 2];
    }
    float hown = 0.0f;   // h0 = 0

    // poll pointers into THIS block's replica: thread tid owns words
    // {m*1024 + tid*4 .. +3}, m = 0..3
    const unsigned rep  = (unsigned)bid & rep_mask;
    const unsigned nrep = rep_mask + 1u;
    const unsigned* pa[2][4];
    #pragma unroll
    for (int m = 0; m < 4; ++m) {
        pa[0][m] = ex0 + rep * R_SIZE + m * 1024 + tid * 4;
        pa[1][m] = ex1 + rep * R_SIZE + m * 1024 + tid * 4;
    }

    __syncthreads();     // xs visible

    // ---- delay-locked pacing state (per wave, wave-uniform scalars) ----
    unsigned long long tgt = 0;   // next poll time; 0 = no pacing yet
    unsigned P = 0;               // sleep ticks after previous publish

    for (int t = 0; t < T_STEPS; ++t) {
        const int par = t & 1;
        unsigned* __restrict__ exw = par ? ex0 : ex1;   // publish tag t+1

        // ---- u = x*Win: independent of h -> compute before the poll ----
        float u = 0.0f;
        if (lane < RPW)
            u = xs[t * 3 + 0] * win0 + xs[t * 3 + 1] * win1 +
                xs[t * 3 + 2] * win2;

        // ---- pace: sleep until predicted arrival (bounded; tgt in the
        //      past no-ops -> free-run; P=0 -> free-run) ----
        if (P) {
            for (int i = 0; i < 4096; ++i) {
                if (__builtin_amdgcn_s_memrealtime() >= tgt) break;
                __builtin_amdgcn_s_sleep(2);
            }
        }

        // ---- poll: first round reads all 16 words; re-rounds only for
        //      lanes still failing (exec-masked -> no traffic). ----
        u32x4 a0, a1, a2, a3;
        const unsigned tg2 = (unsigned)t * 0x00010001u;   // tag splat
        poll16(pa[par][0], pa[par][1], pa[par][2], pa[par][3], a0, a1, a2, a3);
        int ok = check16(a0, a1, a2, a3, tg2);
        const int missed = !__all(ok);
        if (missed) {
            do {
                __builtin_amdgcn_s_sleep(1);
                if (!ok) {
                    poll16(pa[par][0], pa[par][1], pa[par][2], pa[par][3],
                           a0, a1, a2, a3);
                    ok = check16(a0, a1, a2, a3, tg2);
                }
            } while (!__all(ok));
        }

        // ---- unpack to LDS: v_perm lo-half pairs, one 8-B store per m ----
        {
            u32x4 aa[4] = {a0, a1, a2, a3};
            #pragma unroll
            for (int m = 0; m < 4; ++m) {
                u32x2 w;
                w[0] = __builtin_amdgcn_perm(aa[m][1], aa[m][0], 0x05040100u);
                w[1] = __builtin_amdgcn_perm(aa[m][3], aa[m][2], 0x05040100u);
                *(u32x2*)&hl[m * 1024 + tid * 4] = w;
            }
        }
        __syncthreads();   // hl ready for all waves
        // NOTE: no second barrier. A sibling wave's step-t+1 publish (seen
        // by our next poll) data-depends on its step-t hreg reads, so
        // poll-pass at t+1 proves all siblings finished reading hl.

        // ---- per-lane h chunk into registers ----
        h8 hreg[8];
        const h8* hl8 = (const h8*)hl;
        #pragma unroll
        for (int j = 0; j < 8; ++j) hreg[j] = hl8[j * 64 + lane];

        // ---- 4 rows per wave: register weights, dot2-accumulate ----
        float acc[RPW];
        #pragma unroll
        for (int rr = 0; rr < RPW; ++rr) {
            float a = 0.0f;
            #pragma unroll
            for (int j = 0; j < 8; ++j) {
                h8 w8 = wreg[rr * 8 + j];
                h8 hh = hreg[j];
                a = fdot2f(__builtin_shufflevector(w8, w8, 0, 1),
                           __builtin_shufflevector(hh, hh, 0, 1), a);
                a = fdot2f(__builtin_shufflevector(w8, w8, 2, 3),
                           __builtin_shufflevector(hh, hh, 2, 3), a);
                a = fdot2f(__builtin_shufflevector(w8, w8, 4, 5),
                           __builtin_shufflevector(hh, hh, 4, 5), a);
                a = fdot2f(__builtin_shufflevector(w8, w8, 6, 7),
                           __builtin_shufflevector(hh, hh, 6, 7), a);
            }
            acc[rr] = wave_sum(a, idx32, idx48);
        }

        // ---- epilogue: lanes 0-3 finish their row; lanes 0..nrep-1 publish
        //      all replicas with TWO returnless atomic swaps (lane=replica).
        //      Atomics execute at the device coherence point and allocate
        //      in MALL -> no HBM write-through / read-miss round trip. ----
        float hv = 0.0f;
        unsigned word = 0;
        if (lane < RPW) {
            float a = (lane == 0) ? acc[0]
                    : (lane == 1) ? acc[1]
                    : (lane == 2) ? acc[2] : acc[3];
            float hn = fast_tanhf(u + a);
            hv = LEAK * hown + (1.0f - LEAK) * hn;
            hown = hv;
            word = ((unsigned)(t + 1) << 16) |
                   (unsigned)__builtin_bit_cast(unsigned short, (_Float16)hv);
        }
        unsigned w0 = __shfl(word, 0, 64);
        unsigned w1 = __shfl(word, 1, 64);
        unsigned w2 = __shfl(word, 2, 64);
        unsigned w3 = __shfl(word, 3, 64);
        if ((unsigned)lane < nrep) {
            u32x2 lo = {w0, w1};
            u32x2 hi = {w2, w3};
            unsigned* dst = exw + (unsigned)lane * R_SIZE + r0 + wv * RPW;
            asm volatile("global_atomic_swap_x2 %0, %1, off"
                         :: "v"(dst), "v"(lo) : "memory");
            asm volatile("global_atomic_swap_x2 %0, %1, off"
                         :: "v"(dst + 2), "v"(hi) : "memory");
        }

        // ---- DLL bookkeeping off the critical path (post-publish).
        //      miss -> polled too early, +8 ticks; hit -> shave 2. ----
        {
            unsigned long long nowp = __builtin_amdgcn_s_memrealtime();
            P = missed ? (P + 8u > 2048u ? 2048u : P + 8u)
                       : (P >= 2u ? P - 2u : 0u);
            tgt = nowp + P;
        }

        // out[] store after publish — off the critical path
        if (lane < RPW) {
            out[(size_t)t * OUT_COLS + (r0 + wv * RPW + lane)] = hv;
        }
    }
}

__global__ void copy_x_kernel(const float* __restrict__ x, float* __restrict__ out) {
    int i = blockIdx.x * blockDim.x + threadIdx.x;
    if (i < T_STEPS * I_SIZE) {
        int t = i / I_SIZE, c = i % I_SIZE;
        out[(size_t)t * OUT_COLS + R_SIZE + c] = x[i];
    }
}

extern "C" void kernel_launch(void* const* d_in, const int* in_sizes, int n_in,
                              void* d_out, int out_size, void* d_ws, size_t ws_size,
                              hipStream_t stream) {
    // setup_inputs order: x [T,3], Win [R,3], Wh [R,R]; all fp32.
    const float* x   = (const float*)d_in[0];
    const float* Win = (const float*)d_in[1];
    const float* Wh  = (const float*)d_in[2];
    float* out = (float*)d_out;

    // ws layout: ex0 (nrep*16 KB) | ex1 (nrep*16 KB). nrep = 16 -> 512 KB;
    // fall back to 8 (256 KB) then 1 if ws is small.
    size_t need16 = (size_t)2 * 16 * R_SIZE * sizeof(unsigned);   // 512 KB
    size_t need8  = (size_t)2 *  8 * R_SIZE * sizeof(unsigned);   // 256 KB
    unsigned nrep = (ws_size >= need16) ? 16u : (ws_size >= need8 ? 8u : 1u);
    unsigned rep_mask = nrep - 1u;
    unsigned* ex0 = (unsigned*)d_ws;
    unsigned* ex1 = ex0 + (size_t)nrep * R_SIZE;

    // zero both: ex0 all-zero == (tag 0, h=0) = ready state for step 0;
    // ex1 all-zero == tag 0 != 1, so step-1 readers wait.
    (void)hipMemsetAsync(d_ws, 0, (size_t)2 * nrep * R_SIZE * sizeof(unsigned),
                         stream);

    copy_x_kernel<<<dim3((T_STEPS * I_SIZE + BT - 1) / BT), dim3(BT), 0, stream>>>(x, out);

    void* args[] = {(void*)&Wh, (void*)&Win, (void*)&x, (void*)&out,
                    (void*)&ex0, (void*)&ex1, (void*)&rep_mask};
    hipError_t e = hipLaunchCooperativeKernel((void*)esn_kernel, dim3(NB), dim3(BT),
                                              args, 0, stream);
    if (e != hipSuccess) {
        // Fallback: plain launch; 256 blocks x 4 waves always co-resident.
        esn_kernel<<<dim3(NB), dim3(BT), 0, stream>>>(Wh, Win, x, out,
                                                      ex0, ex1, rep_mask);
    }
}

// Round 9
// 8094.319 us; speedup vs baseline: 1.3072x; 1.3072x over previous
//
#include <hip/hip_runtime.h>
#include <cmath>

// ESN forward scan on MI355X — round 12.
//
// Round-11 post-mortem: atomic-swap publish FALSIFIED — FETCH did not
// collapse (597->566 MB), WRITE doubled (2.19->4.29 GB: 8-B atomics cause
// read-modify-write partial-line traffic and serialize at the coherence
// point), dur regressed 8.70->10.58 ms. Exchange is irreducibly
// coherence-point-latency-bound for sc0 sc1 traffic. Publish reverted to
// global_store_dwordx4 sc0 sc1 (round-9 form).
//
// Round 12 = round-9 kernel EXACTLY + the one untested round-11 lever:
// DPP wave-sum. Replaces the 6-dependent-__shfl_xor butterfly (~720 cyc
// ~0.25 us on the serial pre-publish path) with 4 VALU-speed row_ror adds
// + 3 PARALLEL cross-group fetches (ds_swizzle ^16, ds_bpermute ^32/^48 —
// independent, latencies overlap). Chain ~180 cyc. Clean single-delta A/B
// vs round 9's 8.70 ms.
//
// Predicted: dur 8.3-8.6 ms, WRITE back to 2.19 GB, FETCH ~600 MB,
// VALUBusy 21-22%. If >=8.65 ms (null): all lever families exhausted —
// converged at the cross-XCD visibility-latency floor (~2.1 us/step =
// compute 0.55 + store-visibility 0.4 + load-return 0.5 + margin); stop.

#define T_STEPS  4096
#define R_SIZE   4096
#define I_SIZE   3
#define OUT_COLS (R_SIZE + I_SIZE)   // 4099
#define NB       256                 // blocks == CUs; all co-resident
#define BT       256                 // threads per block (4 waves)
#define RPB      16                  // rows per block
#define RPW      4                   // rows per wave
#define NREP     16                  // exchange replicas (fan-in spreading)
#define LEAK     0.1f

typedef _Float16 h2 __attribute__((ext_vector_type(2)));
typedef _Float16 h8 __attribute__((ext_vector_type(8)));
typedef unsigned u32x2 __attribute__((ext_vector_type(2)));
typedef unsigned u32x4 __attribute__((ext_vector_type(4)));

__device__ __forceinline__ float fdot2f(h2 a, h2 b, float c) {
#if __has_builtin(__builtin_amdgcn_fdot2)
    return __builtin_amdgcn_fdot2(a, b, c, false);
#else
    return c + (float)a[0] * (float)b[0] + (float)a[1] * (float)b[1];
#endif
}

// tanh via 2^x: tanh(|s|) = (1-e)/(1+e), e = exp2(-2*log2e*|s|). Error
// ~1e-6, far below the 3.9e-3 fp16 exchange quantization already accepted.
__device__ __forceinline__ float fast_tanhf(float s) {
    float av = __builtin_fabsf(s);
    float e  = __builtin_amdgcn_exp2f(-2.8853900817779268f * av);
    float r  = (1.0f - e) * __builtin_amdgcn_rcpf(1.0f + e);
    return __builtin_copysignf(r, s);
}

// 16 tagged words in flight with L1/L2 bypass, one waitcnt.
__device__ __forceinline__ void poll16(const unsigned* p0, const unsigned* p1,
                                       const unsigned* p2, const unsigned* p3,
                                       u32x4& a0, u32x4& a1, u32x4& a2, u32x4& a3) {
    asm volatile(
        "global_load_dwordx4 %0, %4, off sc0 sc1\n\t"
        "global_load_dwordx4 %1, %5, off sc0 sc1\n\t"
        "global_load_dwordx4 %2, %6, off sc0 sc1\n\t"
        "global_load_dwordx4 %3, %7, off sc0 sc1\n\t"
        "s_waitcnt vmcnt(0)"
        : "=&v"(a0), "=&v"(a1), "=&v"(a2), "=&v"(a3)
        : "v"(p0), "v"(p1), "v"(p2), "v"(p3)
        : "memory");
}

// v_perm-paired tag check: pack two hi-half tags per dword, xor vs splat.
__device__ __forceinline__ unsigned tagbad4(const u32x4& a, unsigned tg2) {
    unsigned t01 = __builtin_amdgcn_perm(a[1], a[0], 0x07060302u) ^ tg2;
    unsigned t23 = __builtin_amdgcn_perm(a[3], a[2], 0x07060302u) ^ tg2;
    return t01 | t23;
}
__device__ __forceinline__ int check16(const u32x4& a0, const u32x4& a1,
                                       const u32x4& a2, const u32x4& a3,
                                       unsigned tg2) {
    unsigned bad = tagbad4(a0, tg2) | tagbad4(a1, tg2) |
                   tagbad4(a2, tg2) | tagbad4(a3, tg2);
    return bad == 0u;
}

// ---- wave-sum, short-chain version ----
// Stage 1: rotate-reduce within each 16-lane DPP row (4 VALU-speed adds):
//   every lane ends with its group's partial sum.
// Stage 2: fetch the other 3 group-partials IN PARALLEL (independent ops:
//   ds_swizzle lane^16 + ds_bpermute lane^32 and lane^48) and add.
template<int CTRL>
__device__ __forceinline__ float dpp_ror_add(float a) {
    int r = __builtin_amdgcn_update_dpp(0, __builtin_bit_cast(int, a),
                                        CTRL, 0xF, 0xF, false);
    return a + __builtin_bit_cast(float, r);
}
__device__ __forceinline__ float wave_sum(float a, int idx32, int idx48) {
    a = dpp_ror_add<0x128>(a);   // row_ror:8
    a = dpp_ror_add<0x124>(a);   // row_ror:4
    a = dpp_ror_add<0x122>(a);   // row_ror:2
    a = dpp_ror_add<0x121>(a);   // row_ror:1
    int ai = __builtin_bit_cast(int, a);
    float b = __builtin_bit_cast(float, __builtin_amdgcn_ds_swizzle(ai, 0x401F)); // lane^16
    float c = __builtin_bit_cast(float, __builtin_amdgcn_ds_bpermute(idx32, ai)); // lane^32
    float d = __builtin_bit_cast(float, __builtin_amdgcn_ds_bpermute(idx48, ai)); // lane^48
    return (a + b) + (c + d);
}

__global__ void __launch_bounds__(BT, 1) esn_kernel(
    const float* __restrict__ Wh,    // [R, R] row-major fp32
    const float* __restrict__ Win,   // [R, 3]
    const float* __restrict__ x,     // [T, 3]
    float* __restrict__ out,         // [T, 4099]
    unsigned* __restrict__ ex0,      // even-step reads: nrep x R dwords
    unsigned* __restrict__ ex1,      // odd-step reads:  nrep x R dwords
    unsigned rep_mask)               // nrep-1 (16/8/1 by ws_size)
{
    __shared__ alignas(16) unsigned short hl[R_SIZE];   // 8 KB fp16 bits
    __shared__ float xs[T_STEPS * I_SIZE];              // 48 KB

    const int tid  = threadIdx.x;
    const int bid  = blockIdx.x;
    const int wv   = tid >> 6;
    const int lane = tid & 63;
    const int r0   = bid * RPB;
    const int idx32 = ((lane ^ 32) << 2);   // bpermute byte indices
    const int idx48 = ((lane ^ 48) << 2);

    // ---- one-time: this wave's 4 Wh rows -> fp16 registers (128 VGPRs) ----
    h8 wreg[RPW * 8];
    #pragma unroll
    for (int rr = 0; rr < RPW; ++rr) {
        const float* src = Wh + (size_t)(r0 + wv * RPW + rr) * R_SIZE;
        #pragma unroll
        for (int j = 0; j < 8; ++j) {
            int e = (j * 64 + lane) * 8;
            float4 a = *(const float4*)(src + e);
            float4 b = *(const float4*)(src + e + 4);
            h8 hv;
            hv[0] = (_Float16)a.x; hv[1] = (_Float16)a.y;
            hv[2] = (_Float16)a.z; hv[3] = (_Float16)a.w;
            hv[4] = (_Float16)b.x; hv[5] = (_Float16)b.y;
            hv[6] = (_Float16)b.z; hv[7] = (_Float16)b.w;
            wreg[rr * 8 + j] = hv;
        }
    }

    // ---- one-time: stage x into LDS ----
    for (int i = tid; i < T_STEPS * I_SIZE; i += BT) xs[i] = x[i];

    // publisher lanes (lane<4) cache their row's Win and fp32 leak state
    float win0 = 0.f, win1 = 0.f, win2 = 0.f;
    if (lane < RPW) {
        int r = r0 + wv * RPW + lane;
        win0 = Win[(size_t)r * I_SIZE + 0];
        win1 = Win[(size_t)r * I_SIZE + 1];
        win2 = Win[(size_t)r * I_SIZE + 2];
    }
    float hown = 0.0f;   // h0 = 0

    // poll pointers into THIS block's replica: thread tid owns words
    // {m*1024 + tid*4 .. +3}, m = 0..3
    const unsigned rep  = (unsigned)bid & rep_mask;
    const unsigned nrep = rep_mask + 1u;
    const unsigned* pa[2][4];
    #pragma unroll
    for (int m = 0; m < 4; ++m) {
        pa[0][m] = ex0 + rep * R_SIZE + m * 1024 + tid * 4;
        pa[1][m] = ex1 + rep * R_SIZE + m * 1024 + tid * 4;
    }

    __syncthreads();     // xs visible

    // ---- delay-locked pacing state (per wave, wave-uniform scalars) ----
    unsigned long long tgt = 0;   // next poll time; 0 = no pacing yet
    unsigned P = 0;               // sleep ticks after previous publish

    for (int t = 0; t < T_STEPS; ++t) {
        const int par = t & 1;
        unsigned* __restrict__ exw = par ? ex0 : ex1;   // publish tag t+1

        // ---- u = x*Win: independent of h -> compute before the poll ----
        float u = 0.0f;
        if (lane < RPW)
            u = xs[t * 3 + 0] * win0 + xs[t * 3 + 1] * win1 +
                xs[t * 3 + 2] * win2;

        // ---- pace: sleep until predicted arrival (bounded; tgt in the
        //      past no-ops -> free-run; P=0 -> free-run) ----
        if (P) {
            for (int i = 0; i < 4096; ++i) {
                if (__builtin_amdgcn_s_memrealtime() >= tgt) break;
                __builtin_amdgcn_s_sleep(2);
            }
        }

        // ---- poll: first round reads all 16 words; re-rounds only for
        //      lanes still failing (exec-masked -> no traffic). ----
        u32x4 a0, a1, a2, a3;
        const unsigned tg2 = (unsigned)t * 0x00010001u;   // tag splat
        poll16(pa[par][0], pa[par][1], pa[par][2], pa[par][3], a0, a1, a2, a3);
        int ok = check16(a0, a1, a2, a3, tg2);
        const int missed = !__all(ok);
        if (missed) {
            do {
                __builtin_amdgcn_s_sleep(1);
                if (!ok) {
                    poll16(pa[par][0], pa[par][1], pa[par][2], pa[par][3],
                           a0, a1, a2, a3);
                    ok = check16(a0, a1, a2, a3, tg2);
                }
            } while (!__all(ok));
        }

        // ---- unpack to LDS: v_perm lo-half pairs, one 8-B store per m ----
        {
            u32x4 aa[4] = {a0, a1, a2, a3};
            #pragma unroll
            for (int m = 0; m < 4; ++m) {
                u32x2 w;
                w[0] = __builtin_amdgcn_perm(aa[m][1], aa[m][0], 0x05040100u);
                w[1] = __builtin_amdgcn_perm(aa[m][3], aa[m][2], 0x05040100u);
                *(u32x2*)&hl[m * 1024 + tid * 4] = w;
            }
        }
        __syncthreads();   // hl ready for all waves
        // NOTE: no second barrier. A sibling wave's step-t+1 publish (seen
        // by our next poll) data-depends on its step-t hreg reads, so
        // poll-pass at t+1 proves all siblings finished reading hl.

        // ---- per-lane h chunk into registers ----
        h8 hreg[8];
        const h8* hl8 = (const h8*)hl;
        #pragma unroll
        for (int j = 0; j < 8; ++j) hreg[j] = hl8[j * 64 + lane];

        // ---- 4 rows per wave: register weights, dot2-accumulate ----
        float acc[RPW];
        #pragma unroll
        for (int rr = 0; rr < RPW; ++rr) {
            float a = 0.0f;
            #pragma unroll
            for (int j = 0; j < 8; ++j) {
                h8 w8 = wreg[rr * 8 + j];
                h8 hh = hreg[j];
                a = fdot2f(__builtin_shufflevector(w8, w8, 0, 1),
                           __builtin_shufflevector(hh, hh, 0, 1), a);
                a = fdot2f(__builtin_shufflevector(w8, w8, 2, 3),
                           __builtin_shufflevector(hh, hh, 2, 3), a);
                a = fdot2f(__builtin_shufflevector(w8, w8, 4, 5),
                           __builtin_shufflevector(hh, hh, 4, 5), a);
                a = fdot2f(__builtin_shufflevector(w8, w8, 6, 7),
                           __builtin_shufflevector(hh, hh, 6, 7), a);
            }
            acc[rr] = wave_sum(a, idx32, idx48);
        }

        // ---- epilogue: lanes 0-3 finish their row; lanes 0..nrep-1 publish
        //      all replicas with ONE packed dwordx4 store (lane=replica). ----
        float hv = 0.0f;
        unsigned word = 0;
        if (lane < RPW) {
            float a = (lane == 0) ? acc[0]
                    : (lane == 1) ? acc[1]
                    : (lane == 2) ? acc[2] : acc[3];
            float hn = fast_tanhf(u + a);
            hv = LEAK * hown + (1.0f - LEAK) * hn;
            hown = hv;
            word = ((unsigned)(t + 1) << 16) |
                   (unsigned)__builtin_bit_cast(unsigned short, (_Float16)hv);
        }
        unsigned w0 = __shfl(word, 0, 64);
        unsigned w1 = __shfl(word, 1, 64);
        unsigned w2 = __shfl(word, 2, 64);
        unsigned w3 = __shfl(word, 3, 64);
        if ((unsigned)lane < nrep) {
            u32x4 pw = {w0, w1, w2, w3};
            unsigned* dst = exw + (unsigned)lane * R_SIZE + r0 + wv * RPW;
            asm volatile("global_store_dwordx4 %0, %1, off sc0 sc1"
                         :: "v"(dst), "v"(pw) : "memory");
        }

        // ---- DLL bookkeeping off the critical path (post-publish).
        //      miss -> polled too early, +8 ticks; hit -> shave 2. ----
        {
            unsigned long long nowp = __builtin_amdgcn_s_memrealtime();
            P = missed ? (P + 8u > 2048u ? 2048u : P + 8u)
                       : (P >= 2u ? P - 2u : 0u);
            tgt = nowp + P;
        }

        // out[] store after publish — off the critical path
        if (lane < RPW) {
            out[(size_t)t * OUT_COLS + (r0 + wv * RPW + lane)] = hv;
        }
    }
}

__global__ void copy_x_kernel(const float* __restrict__ x, float* __restrict__ out) {
    int i = blockIdx.x * blockDim.x + threadIdx.x;
    if (i < T_STEPS * I_SIZE) {
        int t = i / I_SIZE, c = i % I_SIZE;
        out[(size_t)t * OUT_COLS + R_SIZE + c] = x[i];
    }
}

extern "C" void kernel_launch(void* const* d_in, const int* in_sizes, int n_in,
                              void* d_out, int out_size, void* d_ws, size_t ws_size,
                              hipStream_t stream) {
    // setup_inputs order: x [T,3], Win [R,3], Wh [R,R]; all fp32.
    const float* x   = (const float*)d_in[0];
    const float* Win = (const float*)d_in[1];
    const float* Wh  = (const float*)d_in[2];
    float* out = (float*)d_out;

    // ws layout: ex0 (nrep*16 KB) | ex1 (nrep*16 KB). nrep = 16 -> 512 KB;
    // fall back to 8 (256 KB) then 1 if ws is small.
    size_t need16 = (size_t)2 * 16 * R_SIZE * sizeof(unsigned);   // 512 KB
    size_t need8  = (size_t)2 *  8 * R_SIZE * sizeof(unsigned);   // 256 KB
    unsigned nrep = (ws_size >= need16) ? 16u : (ws_size >= need8 ? 8u : 1u);
    unsigned rep_mask = nrep - 1u;
    unsigned* ex0 = (unsigned*)d_ws;
    unsigned* ex1 = ex0 + (size_t)nrep * R_SIZE;

    // zero both: ex0 all-zero == (tag 0, h=0) = ready state for step 0;
    // ex1 all-zero == tag 0 != 1, so step-1 readers wait.
    (void)hipMemsetAsync(d_ws, 0, (size_t)2 * nrep * R_SIZE * sizeof(unsigned),
                         stream);

    copy_x_kernel<<<dim3((T_STEPS * I_SIZE + BT - 1) / BT), dim3(BT), 0, stream>>>(x, out);

    void* args[] = {(void*)&Wh, (void*)&Win, (void*)&x, (void*)&out,
                    (void*)&ex0, (void*)&ex1, (void*)&rep_mask};
    hipError_t e = hipLaunchCooperativeKernel((void*)esn_kernel, dim3(NB), dim3(BT),
                                              args, 0, stream);
    if (e != hipSuccess) {
        // Fallback: plain launch; 256 blocks x 4 waves always co-resident.
        esn_kernel<<<dim3(NB), dim3(BT), 0, stream>>>(Wh, Win, x, out,
                                                      ex0, ex1, rep_mask);
    }
}